// Round 1
// baseline (2278.478 us; speedup 1.0000x reference)
//
#include <hip/hip_runtime.h>
#include <cmath>

typedef __attribute__((ext_vector_type(4))) float f4;
typedef __attribute__((ext_vector_type(8))) short s8;
typedef unsigned short u16;

#define N_TOK 2048
#define DIM   1024
#define NHEAD 16
#define DH    64
#define NE    8
#define FF    4096
#define SEQ   1024

__device__ __forceinline__ u16 f2bf(float f) {
    union { float fp; unsigned int u; } un; un.fp = f;
    unsigned int r = un.u + 0x7FFFu + ((un.u >> 16) & 1u);
    return (u16)(r >> 16);
}

// ---------------- transpose fp32 [R,C] -> bf16 [C,R] (B^T for GEMM) ----------------
__global__ __launch_bounds__(256) void transposeK(const float* __restrict__ in,
                                                  u16* __restrict__ outp,
                                                  int R, int C, long sInZ, long sOutZ) {
    in += (long)blockIdx.z * sInZ;
    outp += (long)blockIdx.z * sOutZ;
    __shared__ float tile[32][33];
    int c0 = blockIdx.x * 32, r0 = blockIdx.y * 32;
    int c = threadIdx.x & 31, rq = threadIdx.x >> 5;   // rq 0..7
#pragma unroll
    for (int p = 0; p < 4; p++)
        tile[rq + p * 8][c] = in[(long)(r0 + rq + p * 8) * C + c0 + c];
    __syncthreads();
#pragma unroll
    for (int p = 0; p < 4; p++) {
        int cc = rq + p * 8;
        outp[(long)(c0 + cc) * R + r0 + c] = f2bf(tile[c][cc]);
    }
}

__global__ void biaspack(const float* bq, const float* bk, const float* bv, float* dst) {
    int z = blockIdx.x;
    const float* s = (z == 0) ? bq : ((z == 1) ? bk : bv);
    for (int i = threadIdx.x; i < DIM; i += 256) dst[z * DIM + i] = s[i];
}

// ---------------- LayerNorm -> bf16 rows ----------------
__global__ __launch_bounds__(256) void ln_kernel(const float* __restrict__ x,
                                                 const float* __restrict__ g,
                                                 const float* __restrict__ b,
                                                 u16* __restrict__ o) {
    int n = blockIdx.x, tid = threadIdx.x;
    f4 v = ((const f4*)(x + (long)n * DIM))[tid];
    float s = v.x + v.y + v.z + v.w;
    float ss = v.x * v.x + v.y * v.y + v.z * v.z + v.w * v.w;
    __shared__ float red[16];
#pragma unroll
    for (int off = 32; off; off >>= 1) { s += __shfl_down(s, off); ss += __shfl_down(ss, off); }
    int w = tid >> 6;
    if ((tid & 63) == 0) { red[w] = s; red[8 + w] = ss; }
    __syncthreads();
    s = red[0] + red[1] + red[2] + red[3];
    ss = red[8] + red[9] + red[10] + red[11];
    float mu = s * (1.0f / DIM);
    float var = ss * (1.0f / DIM) - mu * mu;
    float rstd = rsqrtf(var + 1e-5f);
    f4 gv = ((const f4*)g)[tid], bv = ((const f4*)b)[tid];
    ushort4 pk;
    pk.x = f2bf((v.x - mu) * rstd * gv.x + bv.x);
    pk.y = f2bf((v.y - mu) * rstd * gv.y + bv.y);
    pk.z = f2bf((v.z - mu) * rstd * gv.z + bv.z);
    pk.w = f2bf((v.w - mu) * rstd * gv.w + bv.w);
    ((ushort4*)(o + (long)n * DIM))[tid] = pk;
}

// ---------------- generic 128x128x32 bf16 MFMA GEMM ----------------
// C[M,N] = A[M,K] @ BT[N,K]^T + bias ;  EPI: 0 = f32 store, 1 = f32 + residual, 2 = GELU -> bf16
#define BM 128
#define BN 128
#define BK 32
#define LDK 40   // 32 + 8 pad shorts -> 80B row stride, 2-way-max LDS conflicts

template <int EPI, bool GATHER, bool USEOFF>
__global__ __launch_bounds__(256) void gemm_k(
    const u16* __restrict__ A, long strideAz,
    const u16* __restrict__ BT, long strideBz,
    const float* __restrict__ bias, long strideBiasz,
    float* __restrict__ Cf, u16* __restrict__ Cb, long strideCz,
    const float* __restrict__ res,
    const int* __restrict__ rowlist, int rlStride,
    const int* __restrict__ cnt_p, const int* __restrict__ off_p,
    int M, int N, int K) {
    int z = blockIdx.z;
    int Mv = cnt_p ? cnt_p[z] : M;
    int m0 = blockIdx.y * BM;
    if (m0 >= Mv) return;
    int n0 = blockIdx.x * BN;
    int off = (USEOFF && off_p) ? off_p[z] : 0;
    A += z * strideAz;
    BT += z * strideBz;
    bias += z * strideBiasz;

    __shared__ u16 As[BM * LDK];
    __shared__ u16 Bs[BN * LDK];

    int tid = threadIdx.x;
    int r0 = tid >> 2, seg = tid & 3;

    auto srcrow = [&](int r) -> long {
        int i = m0 + r;
        if (GATHER) {
            int ii = (i < Mv) ? rowlist[z * rlStride + i] : 0;
            return (long)ii;
        } else {
            int ii = (i < Mv) ? i : (Mv - 1);
            return (long)ii + (USEOFF ? (long)off : 0L);
        }
    };

    const u16* aSrc0 = A + srcrow(r0) * K + seg * 8;
    const u16* aSrc1 = A + srcrow(r0 + 64) * K + seg * 8;
    const u16* bSrc0 = BT + (long)(n0 + r0) * K + seg * 8;
    const u16* bSrc1 = BT + (long)(n0 + r0 + 64) * K + seg * 8;
    uint4* asD0 = (uint4*)(As + r0 * LDK + seg * 8);
    uint4* asD1 = (uint4*)(As + (r0 + 64) * LDK + seg * 8);
    uint4* bsD0 = (uint4*)(Bs + r0 * LDK + seg * 8);
    uint4* bsD1 = (uint4*)(Bs + (r0 + 64) * LDK + seg * 8);

    f4 acc[4][4] = {};
    int lane = tid & 63;
    int w = tid >> 6, wm = w & 1, wn = w >> 1;
    int fr = lane & 15, kq = (lane >> 4) * 8;

    for (int kb = 0; kb < K; kb += BK) {
        uint4 va0 = *(const uint4*)aSrc0; aSrc0 += BK;
        uint4 va1 = *(const uint4*)aSrc1; aSrc1 += BK;
        uint4 vb0 = *(const uint4*)bSrc0; bSrc0 += BK;
        uint4 vb1 = *(const uint4*)bSrc1; bSrc1 += BK;
        __syncthreads();
        *asD0 = va0; *asD1 = va1; *bsD0 = vb0; *bsD1 = vb1;
        __syncthreads();
        s8 af[4], bfv[4];
#pragma unroll
        for (int t = 0; t < 4; t++) {
            af[t]  = *(const s8*)(As + (wm * 64 + t * 16 + fr) * LDK + kq);
            bfv[t] = *(const s8*)(Bs + (wn * 64 + t * 16 + fr) * LDK + kq);
        }
#pragma unroll
        for (int mt = 0; mt < 4; mt++)
#pragma unroll
            for (int nt = 0; nt < 4; nt++)
                acc[mt][nt] = __builtin_amdgcn_mfma_f32_16x16x32_bf16(af[mt], bfv[nt], acc[mt][nt], 0, 0, 0);
    }

#pragma unroll
    for (int nt = 0; nt < 4; nt++) {
        int col = n0 + wn * 64 + nt * 16 + fr;
        float bv = bias[col];
#pragma unroll
        for (int mt = 0; mt < 4; mt++) {
            int rbase = m0 + wm * 64 + mt * 16 + (lane >> 4) * 4;
#pragma unroll
            for (int i = 0; i < 4; i++) {
                int rl = rbase + i;
                if (rl < Mv) {
                    float vvv = acc[mt][nt][i] + bv;
                    long crow = (long)rl + (USEOFF ? off : 0);
                    if (EPI == 0) {
                        Cf[z * strideCz + crow * N + col] = vvv;
                    } else if (EPI == 1) {
                        Cf[crow * (long)N + col] = vvv + res[crow * (long)N + col];
                    } else {
                        float gl = 0.5f * vvv * (1.0f + erff(vvv * 0.70710678118654752f));
                        Cb[crow * (long)N + col] = f2bf(gl);
                    }
                }
            }
        }
    }
}

// ---------------- causal attention: 16 queries/block, 4 waves, 16 lanes/query ----------------
__global__ __launch_bounds__(256) void attn_kernel(const float* __restrict__ qkv, u16* __restrict__ y) {
    __shared__ float sc[16][1024];   // 64 KB
    int bh = blockIdx.y, b = bh >> 4, h = bh & 15;
    int tid = threadIdx.x, w = tid >> 6, lane = tid & 63;
    int qi = lane >> 4, dg = lane & 15;
    int t = blockIdx.x * 16 + w * 4 + qi;
    int sN = blockIdx.x * 16 + w * 4 + 4;   // multiple of 4, covers causal range of this wave
    int slot = w * 4 + qi;

    const float* qp = qkv + ((long)(b * SEQ + t) * DIM + h * DH + dg * 4);
    f4 qv = *(const f4*)qp;
    qv *= 0.125f;   // 1/sqrt(64)
    const float* kbase = qkv + (long)N_TOK * DIM + ((long)b * SEQ * DIM + h * DH + dg * 4);
    const float* vbase = kbase + (long)N_TOK * DIM;

    // phase 1: scores
    for (int s = 0; s < sN; s++) {
        f4 kv = *(const f4*)(kbase + (long)s * DIM);
        float d = qv.x * kv.x + qv.y * kv.y + qv.z * kv.z + qv.w * kv.w;
        d += __shfl_xor(d, 1); d += __shfl_xor(d, 2);
        d += __shfl_xor(d, 4); d += __shfl_xor(d, 8);
        float scv = (s <= t) ? d : -INFINITY;
        if (dg == (s & 15)) sc[slot][s] = scv;
    }
    __syncthreads();
    // phase 2: softmax (16 lanes per query)
    float m = -INFINITY;
    for (int s = dg; s < sN; s += 16) m = fmaxf(m, sc[slot][s]);
    m = fmaxf(m, __shfl_xor(m, 1)); m = fmaxf(m, __shfl_xor(m, 2));
    m = fmaxf(m, __shfl_xor(m, 4)); m = fmaxf(m, __shfl_xor(m, 8));
    float l = 0.f;
    for (int s = dg; s < sN; s += 16) {
        float p = __expf(sc[slot][s] - m);
        sc[slot][s] = p;
        l += p;
    }
    l += __shfl_xor(l, 1); l += __shfl_xor(l, 2);
    l += __shfl_xor(l, 4); l += __shfl_xor(l, 8);
    float linv = 1.0f / l;
    __syncthreads();
    // phase 3: y = P @ V
    f4 acc = {0.f, 0.f, 0.f, 0.f};
    for (int s = 0; s < sN; s += 4) {
        f4 pv = *(const f4*)&sc[slot][s];
        f4 v0 = *(const f4*)(vbase + (long)s * DIM);
        f4 v1 = *(const f4*)(vbase + (long)(s + 1) * DIM);
        f4 v2 = *(const f4*)(vbase + (long)(s + 2) * DIM);
        f4 v3 = *(const f4*)(vbase + (long)(s + 3) * DIM);
        acc += pv.x * v0 + pv.y * v1 + pv.z * v2 + pv.w * v3;
    }
    acc *= linv;
    ushort4 pk;
    pk.x = f2bf(acc.x); pk.y = f2bf(acc.y); pk.z = f2bf(acc.z); pk.w = f2bf(acc.w);
    *(ushort4*)(y + (long)(b * SEQ + t) * DIM + h * DH + dg * 4) = pk;
}

// ---------------- LN2 + gating + routing (fp32 exact logits) ----------------
__global__ __launch_bounds__(256) void gate_kernel(
    const float* __restrict__ x1, const float* __restrict__ g, const float* __restrict__ b,
    const float* __restrict__ wg, const float* __restrict__ bg,
    const float* __restrict__ wn, const float* __restrict__ bn,
    const float* __restrict__ noise, u16* __restrict__ h2,
    float* __restrict__ out_noisy, float* __restrict__ out_gate,
    int* __restrict__ cnt, int* __restrict__ list,
    int* __restrict__ tokE, int* __restrict__ tokP, float* __restrict__ tokW) {
    __shared__ float hrow[DIM];
    __shared__ float red[256 * 16];
    __shared__ float red8[16];
    int n = blockIdx.x, tid = threadIdx.x;
    f4 v = ((const f4*)(x1 + (long)n * DIM))[tid];
    float s = v.x + v.y + v.z + v.w;
    float ss = v.x * v.x + v.y * v.y + v.z * v.z + v.w * v.w;
#pragma unroll
    for (int off = 32; off; off >>= 1) { s += __shfl_down(s, off); ss += __shfl_down(ss, off); }
    int wv_ = tid >> 6;
    if ((tid & 63) == 0) { red8[wv_] = s; red8[8 + wv_] = ss; }
    __syncthreads();
    s = red8[0] + red8[1] + red8[2] + red8[3];
    ss = red8[8] + red8[9] + red8[10] + red8[11];
    float mu = s * (1.0f / DIM);
    float var = ss * (1.0f / DIM) - mu * mu;
    float rstd = rsqrtf(var + 1e-5f);
    f4 gv = ((const f4*)g)[tid], bv = ((const f4*)b)[tid];
    float h0 = (v.x - mu) * rstd * gv.x + bv.x;
    float h1 = (v.y - mu) * rstd * gv.y + bv.y;
    float h2v = (v.z - mu) * rstd * gv.z + bv.z;
    float h3 = (v.w - mu) * rstd * gv.w + bv.w;
    hrow[tid * 4 + 0] = h0; hrow[tid * 4 + 1] = h1;
    hrow[tid * 4 + 2] = h2v; hrow[tid * 4 + 3] = h3;
    ushort4 pk;
    pk.x = f2bf(h0); pk.y = f2bf(h1); pk.z = f2bf(h2v); pk.w = f2bf(h3);
    ((ushort4*)(h2 + (long)n * DIM))[tid] = pk;
    __syncthreads();
    float ag[8] = {0, 0, 0, 0, 0, 0, 0, 0}, an[8] = {0, 0, 0, 0, 0, 0, 0, 0};
    for (int d = tid; d < DIM; d += 256) {
        float hv = hrow[d];
        const f4* wgp = (const f4*)(wg + (long)d * NE);
        f4 w0 = wgp[0], w1 = wgp[1];
        ag[0] += hv * w0.x; ag[1] += hv * w0.y; ag[2] += hv * w0.z; ag[3] += hv * w0.w;
        ag[4] += hv * w1.x; ag[5] += hv * w1.y; ag[6] += hv * w1.z; ag[7] += hv * w1.w;
        const f4* wnp = (const f4*)(wn + (long)d * NE);
        f4 n0v = wnp[0], n1v = wnp[1];
        an[0] += hv * n0v.x; an[1] += hv * n0v.y; an[2] += hv * n0v.z; an[3] += hv * n0v.w;
        an[4] += hv * n1v.x; an[5] += hv * n1v.y; an[6] += hv * n1v.z; an[7] += hv * n1v.w;
    }
#pragma unroll
    for (int j = 0; j < 8; j++) { red[tid * 16 + j] = ag[j]; red[tid * 16 + 8 + j] = an[j]; }
    __syncthreads();
    for (int st = 128; st > 0; st >>= 1) {
        if (tid < st) {
#pragma unroll
            for (int j = 0; j < 16; j++) red[tid * 16 + j] += red[(tid + st) * 16 + j];
        }
        __syncthreads();
    }
    if (tid == 0) {
        float gl[8], nl[8], ny[8];
#pragma unroll
        for (int e = 0; e < 8; e++) { gl[e] = red[e] + bg[e]; nl[e] = red[8 + e] + bn[e]; }
#pragma unroll
        for (int e = 0; e < 8; e++) {
            float xx = nl[e];
            float sp = (xx > 20.f) ? xx : log1pf(expf(xx));
            ny[e] = gl[e] + noise[(long)n * 8 + e] * sp;
        }
#pragma unroll
        for (int e = 0; e < 8; e++) {
            out_noisy[(long)n * 8 + e] = ny[e];
            out_gate[(long)n * 8 + e] = gl[e];
        }
        float mx = ny[0];
#pragma unroll
        for (int e = 1; e < 8; e++) mx = fmaxf(mx, ny[e]);
        float p[8], sum = 0.f;
#pragma unroll
        for (int e = 0; e < 8; e++) { p[e] = expf(ny[e] - mx); sum += p[e]; }
        int e1 = 0;
#pragma unroll
        for (int e = 1; e < 8; e++) if (p[e] > p[e1]) e1 = e;
        int e2 = (e1 == 0) ? 1 : 0;
#pragma unroll
        for (int e = 0; e < 8; e++) if (e != e1 && p[e] > p[e2]) e2 = e;
        float wsum = p[e1] + p[e2];
        float w1 = p[e1] / wsum, w2 = p[e2] / wsum;
        int q1 = atomicAdd(&cnt[e1], 1);
        list[e1 * N_TOK + q1] = n; tokE[2 * n] = e1; tokP[2 * n] = q1; tokW[2 * n] = w1;
        int q2 = atomicAdd(&cnt[e2], 1);
        list[e2 * N_TOK + q2] = n; tokE[2 * n + 1] = e2; tokP[2 * n + 1] = q2; tokW[2 * n + 1] = w2;
    }
}

__global__ void offs_kernel(const int* __restrict__ cnt, int* __restrict__ off) {
    if (threadIdx.x == 0) {
        int a = 0;
#pragma unroll
        for (int e = 0; e < NE; e++) { off[e] = a; a += cnt[e]; }
    }
}

__global__ __launch_bounds__(256) void combine_kernel(
    const float* __restrict__ x, const float* __restrict__ C2, const int* __restrict__ offp,
    const int* __restrict__ tokE, const int* __restrict__ tokP, const float* __restrict__ tokW,
    float* __restrict__ out) {
    int n = blockIdx.x, tid = threadIdx.x;
    int e0 = tokE[2 * n], e1 = tokE[2 * n + 1];
    long s0 = (long)offp[e0] + tokP[2 * n];
    long s1 = (long)offp[e1] + tokP[2 * n + 1];
    float w0 = tokW[2 * n], w1 = tokW[2 * n + 1];
    f4 xv = ((const f4*)(x + (long)n * DIM))[tid];
    f4 a = ((const f4*)(C2 + s0 * DIM))[tid];
    f4 b = ((const f4*)(C2 + s1 * DIM))[tid];
    f4 o = xv + w0 * a + w1 * b;
    ((f4*)(out + (long)n * DIM))[tid] = o;
}

// ---------------- host ----------------
extern "C" void kernel_launch(void* const* d_in, const int* in_sizes, int n_in,
                              void* d_out, int out_size, void* d_ws, size_t ws_size,
                              hipStream_t stream) {
    (void)in_sizes; (void)n_in; (void)out_size; (void)ws_size;
    const float* x     = (const float*)d_in[0];
    const float* noise = (const float*)d_in[1];
    const float* ln1g  = (const float*)d_in[2];
    const float* ln1b  = (const float*)d_in[3];
    const float* ln2g  = (const float*)d_in[4];
    const float* ln2b  = (const float*)d_in[5];
    const float* wq = (const float*)d_in[6];  const float* bq = (const float*)d_in[7];
    const float* wk = (const float*)d_in[8];  const float* bk = (const float*)d_in[9];
    const float* wv = (const float*)d_in[10]; const float* bv = (const float*)d_in[11];
    const float* wp = (const float*)d_in[12]; const float* bp = (const float*)d_in[13];
    const float* wg = (const float*)d_in[14]; const float* bg = (const float*)d_in[15];
    const float* wn = (const float*)d_in[16]; const float* bn = (const float*)d_in[17];
    const float* w_in  = (const float*)d_in[18]; const float* b_in  = (const float*)d_in[19];
    const float* w_out = (const float*)d_in[20]; const float* b_out = (const float*)d_in[21];
    float* out = (float*)d_out;

    char* ws = (char*)d_ws;
    size_t o = 0;
    auto alloc = [&](size_t sz) -> char* { char* p = ws + o; o += (sz + 255) & ~(size_t)255; return p; };
    u16*   hB    = (u16*)alloc((size_t)N_TOK * DIM * 2);
    u16*   wT    = (u16*)alloc(4ull * DIM * DIM * 2);        // wqT,wkT,wvT,wpT
    float* qkv   = (float*)alloc(3ull * N_TOK * DIM * 4);
    u16*   yB    = (u16*)alloc((size_t)N_TOK * DIM * 2);
    float* x1    = (float*)alloc((size_t)N_TOK * DIM * 4);
    u16*   h2B   = (u16*)alloc((size_t)N_TOK * DIM * 2);
    u16*   winT  = (u16*)alloc((size_t)NE * DIM * FF * 2);
    u16*   woutT = (u16*)alloc((size_t)NE * DIM * FF * 2);
    u16*   mid   = (u16*)alloc((size_t)N_TOK * 2 * FF * 2);
    float* C2    = (float*)alloc((size_t)N_TOK * 2 * DIM * 4);
    float* qkvb  = (float*)alloc(3ull * DIM * 4);
    int*   cnt   = (int*)alloc(NE * 4);
    int*   offp  = (int*)alloc(NE * 4);
    int*   list  = (int*)alloc((size_t)NE * N_TOK * 4);
    int*   tokE  = (int*)alloc((size_t)N_TOK * 2 * 4);
    int*   tokP  = (int*)alloc((size_t)N_TOK * 2 * 4);
    float* tokW  = (float*)alloc((size_t)N_TOK * 2 * 4);

    // weight transposes -> bf16 B^T layout
    transposeK<<<dim3(32, 32, 1), 256, 0, stream>>>(wq, wT + 0ull * DIM * DIM, DIM, DIM, 0, 0);
    transposeK<<<dim3(32, 32, 1), 256, 0, stream>>>(wk, wT + 1ull * DIM * DIM, DIM, DIM, 0, 0);
    transposeK<<<dim3(32, 32, 1), 256, 0, stream>>>(wv, wT + 2ull * DIM * DIM, DIM, DIM, 0, 0);
    transposeK<<<dim3(32, 32, 1), 256, 0, stream>>>(wp, wT + 3ull * DIM * DIM, DIM, DIM, 0, 0);
    transposeK<<<dim3(FF / 32, DIM / 32, NE), 256, 0, stream>>>(w_in, winT, DIM, FF, (long)DIM * FF, (long)DIM * FF);
    transposeK<<<dim3(DIM / 32, FF / 32, NE), 256, 0, stream>>>(w_out, woutT, FF, DIM, (long)DIM * FF, (long)DIM * FF);
    biaspack<<<dim3(3), 256, 0, stream>>>(bq, bk, bv, qkvb);

    // LN1 -> h (bf16)
    ln_kernel<<<dim3(N_TOK), 256, 0, stream>>>(x, ln1g, ln1b, hB);
    // QKV projections (z picks q/k/v)
    gemm_k<0, false, false><<<dim3(DIM / BN, N_TOK / BM, 3), 256, 0, stream>>>(
        hB, 0, wT, (long)DIM * DIM, qkvb, DIM, qkv, nullptr, (long)N_TOK * DIM,
        nullptr, nullptr, 0, nullptr, nullptr, N_TOK, DIM, DIM);
    // causal attention -> y (bf16)
    attn_kernel<<<dim3(SEQ / 16, 2 * NHEAD), 256, 0, stream>>>(qkv, yB);
    // out projection + residual -> x1 (fp32)
    gemm_k<1, false, false><<<dim3(DIM / BN, N_TOK / BM, 1), 256, 0, stream>>>(
        yB, 0, wT + 3ull * DIM * DIM, 0, bp, 0, x1, nullptr, 0,
        x, nullptr, 0, nullptr, nullptr, N_TOK, DIM, DIM);
    // gating + routing
    hipMemsetAsync(cnt, 0, NE * sizeof(int), stream);
    gate_kernel<<<dim3(N_TOK), 256, 0, stream>>>(
        x1, ln2g, ln2b, wg, bg, wn, bn, noise, h2B,
        out + 2097152, out + 2097152 + 16384,
        cnt, list, tokE, tokP, tokW);
    offs_kernel<<<dim3(1), 64, 0, stream>>>(cnt, offp);
    // expert FFN, sparse grouped: GEMM1 (GELU->bf16 mid), GEMM2 (fp32 C2)
    gemm_k<2, true, true><<<dim3(FF / BN, N_TOK / BM, NE), 256, 0, stream>>>(
        h2B, 0, winT, (long)DIM * FF, b_in, FF, nullptr, mid, 0,
        nullptr, list, N_TOK, cnt, offp, N_TOK, FF, DIM);
    gemm_k<0, false, true><<<dim3(DIM / BN, N_TOK / BM, NE), 256, 0, stream>>>(
        mid, 0, woutT, (long)DIM * FF, b_out, DIM, C2, nullptr, 0,
        nullptr, nullptr, 0, cnt, offp, N_TOK, DIM, FF);
    // combine + residual (original x)
    combine_kernel<<<dim3(N_TOK), 256, 0, stream>>>(x, C2, offp, tokE, tokP, tokW, out);
}

// Round 2
// 834.443 us; speedup vs baseline: 2.7305x; 2.7305x over previous
//
#include <hip/hip_runtime.h>
#include <cmath>

typedef __attribute__((ext_vector_type(4))) float f4;
typedef __attribute__((ext_vector_type(8))) short s8;
typedef unsigned short u16;

#define N_TOK 2048
#define DIM   1024
#define NHEAD 16
#define DH    64
#define NE    8
#define FF    4096
#define SEQ   1024

__device__ __forceinline__ u16 f2bf(float f) {
    union { float fp; unsigned int u; } un; un.fp = f;
    unsigned int r = un.u + 0x7FFFu + ((un.u >> 16) & 1u);
    return (u16)(r >> 16);
}

// ---------------- transpose fp32 [R,C] -> bf16 [C,R] (B^T for GEMM) ----------------
__global__ __launch_bounds__(256) void transposeK(const float* __restrict__ in,
                                                  u16* __restrict__ outp,
                                                  int R, int C, long sInZ, long sOutZ) {
    in += (long)blockIdx.z * sInZ;
    outp += (long)blockIdx.z * sOutZ;
    __shared__ float tile[32][33];
    int c0 = blockIdx.x * 32, r0 = blockIdx.y * 32;
    int c = threadIdx.x & 31, rq = threadIdx.x >> 5;   // rq 0..7
#pragma unroll
    for (int p = 0; p < 4; p++)
        tile[rq + p * 8][c] = in[(long)(r0 + rq + p * 8) * C + c0 + c];
    __syncthreads();
#pragma unroll
    for (int p = 0; p < 4; p++) {
        int cc = rq + p * 8;
        outp[(long)(c0 + cc) * R + r0 + c] = f2bf(tile[c][cc]);
    }
}

__global__ void biaspack(const float* bq, const float* bk, const float* bv, float* dst) {
    int z = blockIdx.x;
    const float* s = (z == 0) ? bq : ((z == 1) ? bk : bv);
    for (int i = threadIdx.x; i < DIM; i += 256) dst[z * DIM + i] = s[i];
}

// ---------------- LayerNorm -> bf16 rows ----------------
__global__ __launch_bounds__(256) void ln_kernel(const float* __restrict__ x,
                                                 const float* __restrict__ g,
                                                 const float* __restrict__ b,
                                                 u16* __restrict__ o) {
    int n = blockIdx.x, tid = threadIdx.x;
    f4 v = ((const f4*)(x + (long)n * DIM))[tid];
    float s = v.x + v.y + v.z + v.w;
    float ss = v.x * v.x + v.y * v.y + v.z * v.z + v.w * v.w;
    __shared__ float red[16];
#pragma unroll
    for (int off = 32; off; off >>= 1) { s += __shfl_down(s, off); ss += __shfl_down(ss, off); }
    int w = tid >> 6;
    if ((tid & 63) == 0) { red[w] = s; red[8 + w] = ss; }
    __syncthreads();
    s = red[0] + red[1] + red[2] + red[3];
    ss = red[8] + red[9] + red[10] + red[11];
    float mu = s * (1.0f / DIM);
    float var = ss * (1.0f / DIM) - mu * mu;
    float rstd = rsqrtf(var + 1e-5f);
    f4 gv = ((const f4*)g)[tid], bv = ((const f4*)b)[tid];
    ushort4 pk;
    pk.x = f2bf((v.x - mu) * rstd * gv.x + bv.x);
    pk.y = f2bf((v.y - mu) * rstd * gv.y + bv.y);
    pk.z = f2bf((v.z - mu) * rstd * gv.z + bv.z);
    pk.w = f2bf((v.w - mu) * rstd * gv.w + bv.w);
    ((ushort4*)(o + (long)n * DIM))[tid] = pk;
}

// ---------------- generic 128x128x32 bf16 MFMA GEMM ----------------
// EPI: 0 = f32 store (+z), 1 = f32 + residual, 2 = GELU -> bf16, 3 = bf16 store (+z)
#define BM 128
#define BN 128
#define BK 32
#define LDK 40

template <int EPI, bool GATHER, bool USEOFF>
__global__ __launch_bounds__(256) void gemm_k(
    const u16* __restrict__ A, long strideAz,
    const u16* __restrict__ BT, long strideBz,
    const float* __restrict__ bias, long strideBiasz,
    float* __restrict__ Cf, u16* __restrict__ Cb, long strideCz,
    const float* __restrict__ res,
    const int* __restrict__ rowlist, int rlStride,
    const int* __restrict__ cnt_p, const int* __restrict__ off_p,
    int M, int N, int K) {
    int z = blockIdx.z;
    int Mv = cnt_p ? cnt_p[z] : M;
    int m0 = blockIdx.y * BM;
    if (m0 >= Mv) return;
    int n0 = blockIdx.x * BN;
    int off = (USEOFF && off_p) ? off_p[z] : 0;
    A += z * strideAz;
    BT += z * strideBz;
    bias += z * strideBiasz;

    __shared__ u16 As[BM * LDK];
    __shared__ u16 Bs[BN * LDK];

    int tid = threadIdx.x;
    int r0 = tid >> 2, seg = tid & 3;

    auto srcrow = [&](int r) -> long {
        int i = m0 + r;
        if (GATHER) {
            int ii = (i < Mv) ? rowlist[z * rlStride + i] : 0;
            return (long)ii;
        } else {
            int ii = (i < Mv) ? i : (Mv - 1);
            return (long)ii + (USEOFF ? (long)off : 0L);
        }
    };

    const u16* aSrc0 = A + srcrow(r0) * K + seg * 8;
    const u16* aSrc1 = A + srcrow(r0 + 64) * K + seg * 8;
    const u16* bSrc0 = BT + (long)(n0 + r0) * K + seg * 8;
    const u16* bSrc1 = BT + (long)(n0 + r0 + 64) * K + seg * 8;
    uint4* asD0 = (uint4*)(As + r0 * LDK + seg * 8);
    uint4* asD1 = (uint4*)(As + (r0 + 64) * LDK + seg * 8);
    uint4* bsD0 = (uint4*)(Bs + r0 * LDK + seg * 8);
    uint4* bsD1 = (uint4*)(Bs + (r0 + 64) * LDK + seg * 8);

    f4 acc[4][4] = {};
    int lane = tid & 63;
    int w = tid >> 6, wm = w & 1, wn = w >> 1;
    int fr = lane & 15, kq = (lane >> 4) * 8;

    for (int kb = 0; kb < K; kb += BK) {
        uint4 va0 = *(const uint4*)aSrc0; aSrc0 += BK;
        uint4 va1 = *(const uint4*)aSrc1; aSrc1 += BK;
        uint4 vb0 = *(const uint4*)bSrc0; bSrc0 += BK;
        uint4 vb1 = *(const uint4*)bSrc1; bSrc1 += BK;
        __syncthreads();
        *asD0 = va0; *asD1 = va1; *bsD0 = vb0; *bsD1 = vb1;
        __syncthreads();
        s8 af[4], bfv[4];
#pragma unroll
        for (int t = 0; t < 4; t++) {
            af[t]  = *(const s8*)(As + (wm * 64 + t * 16 + fr) * LDK + kq);
            bfv[t] = *(const s8*)(Bs + (wn * 64 + t * 16 + fr) * LDK + kq);
        }
#pragma unroll
        for (int mt = 0; mt < 4; mt++)
#pragma unroll
            for (int nt = 0; nt < 4; nt++)
                acc[mt][nt] = __builtin_amdgcn_mfma_f32_16x16x32_bf16(af[mt], bfv[nt], acc[mt][nt], 0, 0, 0);
    }

#pragma unroll
    for (int nt = 0; nt < 4; nt++) {
        int col = n0 + wn * 64 + nt * 16 + fr;
        float bv = bias[col];
#pragma unroll
        for (int mt = 0; mt < 4; mt++) {
            int rbase = m0 + wm * 64 + mt * 16 + (lane >> 4) * 4;
#pragma unroll
            for (int i = 0; i < 4; i++) {
                int rl = rbase + i;
                if (rl < Mv) {
                    float vvv = acc[mt][nt][i] + bv;
                    long crow = (long)rl + (USEOFF ? off : 0);
                    if (EPI == 0) {
                        Cf[z * strideCz + crow * N + col] = vvv;
                    } else if (EPI == 1) {
                        Cf[crow * (long)N + col] = vvv + res[crow * (long)N + col];
                    } else if (EPI == 2) {
                        float gl = 0.5f * vvv * (1.0f + erff(vvv * 0.70710678118654752f));
                        Cb[crow * (long)N + col] = f2bf(gl);
                    } else {
                        Cb[z * strideCz + crow * N + col] = f2bf(vvv);
                    }
                }
            }
        }
    }
}

// ---------------- MFMA flash attention ----------------
// grid (8 q-tiles, B*H). 256 thr = 4 waves, each wave owns 32 q rows.
// K/V tiles of 64 keys; V staged transposed; P via per-wave LDS round-trip.
#define ALDK 72   // 64 + 8 pad (u16) -> 144B row stride, 2-way max conflicts

__global__ __launch_bounds__(256) void fattn_kernel(const u16* __restrict__ qkv,
                                                    u16* __restrict__ y) {
    __shared__ u16 Qs[128 * ALDK];      // 18432 B
    __shared__ u16 Ks[64 * ALDK];       //  9216 B
    __shared__ u16 Vs[64 * ALDK];       //  9216 B  [d][s]
    __shared__ u16 Ps[4][32 * ALDK];    // 18432 B  per-wave P
    int qt = blockIdx.x;
    int bh = blockIdx.y, b = bh >> 4, h = bh & 15;
    int tid = threadIdx.x, w = tid >> 6, lane = tid & 63;
    int fr = lane & 15, quad = lane >> 4;

    const u16* Qg = qkv + ((long)(b * SEQ + qt * 128) * DIM + h * DH);
    const u16* Kg = qkv + (long)N_TOK * DIM + ((long)b * SEQ * DIM + h * DH);
    const u16* Vg = Kg + (long)N_TOK * DIM;

    // stage Q tile (128 x 64)
#pragma unroll
    for (int p = 0; p < 4; p++) {
        int item = tid + p * 256;
        int r = item >> 3, seg = item & 7;
        *(uint4*)(Qs + r * ALDK + seg * 8) = *(const uint4*)(Qg + (long)r * DIM + seg * 8);
    }
    __syncthreads();

    // Q A-frags in registers [mt][kk]
    s8 qf[2][2];
    int qrow = w * 32;
#pragma unroll
    for (int mt = 0; mt < 2; mt++)
#pragma unroll
        for (int kk = 0; kk < 2; kk++)
            qf[mt][kk] = *(const s8*)(Qs + (qrow + mt * 16 + fr) * ALDK + kk * 32 + quad * 8);

    f4 o_acc[2][4] = {};
    float m_run[2][4], l_run[2][4];
#pragma unroll
    for (int mt = 0; mt < 2; mt++)
#pragma unroll
        for (int i = 0; i < 4; i++) { m_run[mt][i] = -INFINITY; l_run[mt][i] = 0.f; }

    int qb_wave = qt * 128 + w * 32;
    int nkt = 2 * qt + 2;
    for (int kt = 0; kt < nkt; kt++) {
        __syncthreads();   // previous iter's Ks/Vs consumers done
        // stage K (rows) and V (transposed)
#pragma unroll
        for (int p = 0; p < 2; p++) {
            int item = tid + p * 256;
            int r = item >> 3, seg = item & 7;
            *(uint4*)(Ks + r * ALDK + seg * 8) =
                *(const uint4*)(Kg + (long)(kt * 64 + r) * DIM + seg * 8);
            uint4 vv = *(const uint4*)(Vg + (long)(kt * 64 + r) * DIM + seg * 8);
            const u16* vp = (const u16*)&vv;
#pragma unroll
            for (int j = 0; j < 8; j++)
                Vs[(seg * 8 + j) * ALDK + r] = vp[j];
        }
        __syncthreads();

        bool act = (kt * 64 <= qb_wave + 31);
        if (act) {
            // S = Q K^T
            f4 s_acc[2][4] = {};
#pragma unroll
            for (int kk = 0; kk < 2; kk++) {
                s8 bf[4];
#pragma unroll
                for (int nt = 0; nt < 4; nt++)
                    bf[nt] = *(const s8*)(Ks + (nt * 16 + fr) * ALDK + kk * 32 + quad * 8);
#pragma unroll
                for (int mt = 0; mt < 2; mt++)
#pragma unroll
                    for (int nt = 0; nt < 4; nt++)
                        s_acc[mt][nt] = __builtin_amdgcn_mfma_f32_16x16x32_bf16(
                            qf[mt][kk], bf[nt], s_acc[mt][nt], 0, 0, 0);
            }
            // scale + causal mask
#pragma unroll
            for (int mt = 0; mt < 2; mt++)
#pragma unroll
                for (int i = 0; i < 4; i++) {
                    int t_ = qb_wave + mt * 16 + quad * 4 + i;
#pragma unroll
                    for (int nt = 0; nt < 4; nt++) {
                        int s_ = kt * 64 + nt * 16 + fr;
                        float sv = s_acc[mt][nt][i] * 0.125f;
                        s_acc[mt][nt][i] = (s_ <= t_) ? sv : -1e30f;
                    }
                }
            // online softmax
#pragma unroll
            for (int mt = 0; mt < 2; mt++)
#pragma unroll
                for (int i = 0; i < 4; i++) {
                    float rm = s_acc[mt][0][i];
#pragma unroll
                    for (int nt = 1; nt < 4; nt++) rm = fmaxf(rm, s_acc[mt][nt][i]);
                    rm = fmaxf(rm, __shfl_xor(rm, 1));
                    rm = fmaxf(rm, __shfl_xor(rm, 2));
                    rm = fmaxf(rm, __shfl_xor(rm, 4));
                    rm = fmaxf(rm, __shfl_xor(rm, 8));
                    float mn = fmaxf(m_run[mt][i], rm);
                    float alpha = __expf(m_run[mt][i] - mn);
                    m_run[mt][i] = mn;
                    float rs = 0.f;
#pragma unroll
                    for (int nt = 0; nt < 4; nt++) {
                        float p = __expf(s_acc[mt][nt][i] - mn);
                        s_acc[mt][nt][i] = p;
                        rs += p;
                    }
                    rs += __shfl_xor(rs, 1);
                    rs += __shfl_xor(rs, 2);
                    rs += __shfl_xor(rs, 4);
                    rs += __shfl_xor(rs, 8);
                    l_run[mt][i] = alpha * l_run[mt][i] + rs;
#pragma unroll
                    for (int dt = 0; dt < 4; dt++) o_acc[mt][dt][i] *= alpha;
                }
            // P -> LDS (C-layout -> A-layout)
            u16* Pw = Ps[w];
#pragma unroll
            for (int mt = 0; mt < 2; mt++)
#pragma unroll
                for (int nt = 0; nt < 4; nt++)
#pragma unroll
                    for (int i = 0; i < 4; i++)
                        Pw[(mt * 16 + quad * 4 + i) * ALDK + nt * 16 + fr] =
                            f2bf(s_acc[mt][nt][i]);
        }
        __syncthreads();   // also orders wave's own P writes (lgkmcnt drain)
        if (act) {
            // O += P V
            u16* Pw = Ps[w];
#pragma unroll
            for (int kk = 0; kk < 2; kk++) {
                s8 pf[2], vf[4];
#pragma unroll
                for (int mt = 0; mt < 2; mt++)
                    pf[mt] = *(const s8*)(Pw + (mt * 16 + fr) * ALDK + kk * 32 + quad * 8);
#pragma unroll
                for (int dt = 0; dt < 4; dt++)
                    vf[dt] = *(const s8*)(Vs + (dt * 16 + fr) * ALDK + kk * 32 + quad * 8);
#pragma unroll
                for (int mt = 0; mt < 2; mt++)
#pragma unroll
                    for (int dt = 0; dt < 4; dt++)
                        o_acc[mt][dt] = __builtin_amdgcn_mfma_f32_16x16x32_bf16(
                            pf[mt], vf[dt], o_acc[mt][dt], 0, 0, 0);
            }
        }
    }
    // epilogue
#pragma unroll
    for (int mt = 0; mt < 2; mt++)
#pragma unroll
        for (int i = 0; i < 4; i++) {
            float linv = 1.0f / l_run[mt][i];
            int t_ = qt * 128 + w * 32 + mt * 16 + quad * 4 + i;
            u16* yrow = y + (long)(b * SEQ + t_) * DIM + h * DH;
#pragma unroll
            for (int dt = 0; dt < 4; dt++)
                yrow[dt * 16 + fr] = f2bf(o_acc[mt][dt][i] * linv);
        }
}

// ---------------- LN2 + gating + routing (fp32 exact logits) ----------------
__global__ __launch_bounds__(256) void gate_kernel(
    const float* __restrict__ x1, const float* __restrict__ g, const float* __restrict__ b,
    const float* __restrict__ wg, const float* __restrict__ bg,
    const float* __restrict__ wn, const float* __restrict__ bn,
    const float* __restrict__ noise, u16* __restrict__ h2,
    float* __restrict__ out_noisy, float* __restrict__ out_gate,
    int* __restrict__ cnt, int* __restrict__ list,
    int* __restrict__ tokE, int* __restrict__ tokP, float* __restrict__ tokW) {
    __shared__ float hrow[DIM];
    __shared__ float red[256 * 16];
    __shared__ float red8[16];
    int n = blockIdx.x, tid = threadIdx.x;
    f4 v = ((const f4*)(x1 + (long)n * DIM))[tid];
    float s = v.x + v.y + v.z + v.w;
    float ss = v.x * v.x + v.y * v.y + v.z * v.z + v.w * v.w;
#pragma unroll
    for (int off = 32; off; off >>= 1) { s += __shfl_down(s, off); ss += __shfl_down(ss, off); }
    int wv_ = tid >> 6;
    if ((tid & 63) == 0) { red8[wv_] = s; red8[8 + wv_] = ss; }
    __syncthreads();
    s = red8[0] + red8[1] + red8[2] + red8[3];
    ss = red8[8] + red8[9] + red8[10] + red8[11];
    float mu = s * (1.0f / DIM);
    float var = ss * (1.0f / DIM) - mu * mu;
    float rstd = rsqrtf(var + 1e-5f);
    f4 gv = ((const f4*)g)[tid], bv = ((const f4*)b)[tid];
    float h0 = (v.x - mu) * rstd * gv.x + bv.x;
    float h1 = (v.y - mu) * rstd * gv.y + bv.y;
    float h2v = (v.z - mu) * rstd * gv.z + bv.z;
    float h3 = (v.w - mu) * rstd * gv.w + bv.w;
    hrow[tid * 4 + 0] = h0; hrow[tid * 4 + 1] = h1;
    hrow[tid * 4 + 2] = h2v; hrow[tid * 4 + 3] = h3;
    ushort4 pk;
    pk.x = f2bf(h0); pk.y = f2bf(h1); pk.z = f2bf(h2v); pk.w = f2bf(h3);
    ((ushort4*)(h2 + (long)n * DIM))[tid] = pk;
    __syncthreads();
    float ag[8] = {0, 0, 0, 0, 0, 0, 0, 0}, an[8] = {0, 0, 0, 0, 0, 0, 0, 0};
    for (int d = tid; d < DIM; d += 256) {
        float hv = hrow[d];
        const f4* wgp = (const f4*)(wg + (long)d * NE);
        f4 w0 = wgp[0], w1 = wgp[1];
        ag[0] += hv * w0.x; ag[1] += hv * w0.y; ag[2] += hv * w0.z; ag[3] += hv * w0.w;
        ag[4] += hv * w1.x; ag[5] += hv * w1.y; ag[6] += hv * w1.z; ag[7] += hv * w1.w;
        const f4* wnp = (const f4*)(wn + (long)d * NE);
        f4 n0v = wnp[0], n1v = wnp[1];
        an[0] += hv * n0v.x; an[1] += hv * n0v.y; an[2] += hv * n0v.z; an[3] += hv * n0v.w;
        an[4] += hv * n1v.x; an[5] += hv * n1v.y; an[6] += hv * n1v.z; an[7] += hv * n1v.w;
    }
#pragma unroll
    for (int j = 0; j < 8; j++) { red[tid * 16 + j] = ag[j]; red[tid * 16 + 8 + j] = an[j]; }
    __syncthreads();
    for (int st = 128; st > 0; st >>= 1) {
        if (tid < st) {
#pragma unroll
            for (int j = 0; j < 16; j++) red[tid * 16 + j] += red[(tid + st) * 16 + j];
        }
        __syncthreads();
    }
    if (tid == 0) {
        float gl[8], nl[8], ny[8];
#pragma unroll
        for (int e = 0; e < 8; e++) { gl[e] = red[e] + bg[e]; nl[e] = red[8 + e] + bn[e]; }
#pragma unroll
        for (int e = 0; e < 8; e++) {
            float xx = nl[e];
            float sp = (xx > 20.f) ? xx : log1pf(expf(xx));
            ny[e] = gl[e] + noise[(long)n * 8 + e] * sp;
        }
#pragma unroll
        for (int e = 0; e < 8; e++) {
            out_noisy[(long)n * 8 + e] = ny[e];
            out_gate[(long)n * 8 + e] = gl[e];
        }
        float mx = ny[0];
#pragma unroll
        for (int e = 1; e < 8; e++) mx = fmaxf(mx, ny[e]);
        float p[8], sum = 0.f;
#pragma unroll
        for (int e = 0; e < 8; e++) { p[e] = expf(ny[e] - mx); sum += p[e]; }
        int e1 = 0;
#pragma unroll
        for (int e = 1; e < 8; e++) if (p[e] > p[e1]) e1 = e;
        int e2 = (e1 == 0) ? 1 : 0;
#pragma unroll
        for (int e = 0; e < 8; e++) if (e != e1 && p[e] > p[e2]) e2 = e;
        float wsum = p[e1] + p[e2];
        float w1 = p[e1] / wsum, w2 = p[e2] / wsum;
        int q1 = atomicAdd(&cnt[e1], 1);
        list[e1 * N_TOK + q1] = n; tokE[2 * n] = e1; tokP[2 * n] = q1; tokW[2 * n] = w1;
        int q2 = atomicAdd(&cnt[e2], 1);
        list[e2 * N_TOK + q2] = n; tokE[2 * n + 1] = e2; tokP[2 * n + 1] = q2; tokW[2 * n + 1] = w2;
    }
}

__global__ void offs_kernel(const int* __restrict__ cnt, int* __restrict__ off) {
    if (threadIdx.x == 0) {
        int a = 0;
#pragma unroll
        for (int e = 0; e < NE; e++) { off[e] = a; a += cnt[e]; }
    }
}

__global__ __launch_bounds__(256) void combine_kernel(
    const float* __restrict__ x, const float* __restrict__ C2, const int* __restrict__ offp,
    const int* __restrict__ tokE, const int* __restrict__ tokP, const float* __restrict__ tokW,
    float* __restrict__ out) {
    int n = blockIdx.x, tid = threadIdx.x;
    int e0 = tokE[2 * n], e1 = tokE[2 * n + 1];
    long s0 = (long)offp[e0] + tokP[2 * n];
    long s1 = (long)offp[e1] + tokP[2 * n + 1];
    float w0 = tokW[2 * n], w1 = tokW[2 * n + 1];
    f4 xv = ((const f4*)(x + (long)n * DIM))[tid];
    f4 a = ((const f4*)(C2 + s0 * DIM))[tid];
    f4 b = ((const f4*)(C2 + s1 * DIM))[tid];
    f4 o = xv + w0 * a + w1 * b;
    ((f4*)(out + (long)n * DIM))[tid] = o;
}

// ---------------- host ----------------
extern "C" void kernel_launch(void* const* d_in, const int* in_sizes, int n_in,
                              void* d_out, int out_size, void* d_ws, size_t ws_size,
                              hipStream_t stream) {
    (void)in_sizes; (void)n_in; (void)out_size; (void)ws_size;
    const float* x     = (const float*)d_in[0];
    const float* noise = (const float*)d_in[1];
    const float* ln1g  = (const float*)d_in[2];
    const float* ln1b  = (const float*)d_in[3];
    const float* ln2g  = (const float*)d_in[4];
    const float* ln2b  = (const float*)d_in[5];
    const float* wq = (const float*)d_in[6];  const float* bq = (const float*)d_in[7];
    const float* wk = (const float*)d_in[8];  const float* bk = (const float*)d_in[9];
    const float* wv = (const float*)d_in[10]; const float* bv = (const float*)d_in[11];
    const float* wp = (const float*)d_in[12]; const float* bp = (const float*)d_in[13];
    const float* wg = (const float*)d_in[14]; const float* bg = (const float*)d_in[15];
    const float* wn = (const float*)d_in[16]; const float* bn = (const float*)d_in[17];
    const float* w_in  = (const float*)d_in[18]; const float* b_in  = (const float*)d_in[19];
    const float* w_out = (const float*)d_in[20]; const float* b_out = (const float*)d_in[21];
    float* out = (float*)d_out;

    char* ws = (char*)d_ws;
    size_t o = 0;
    auto alloc = [&](size_t sz) -> char* { char* p = ws + o; o += (sz + 255) & ~(size_t)255; return p; };
    u16*   hB    = (u16*)alloc((size_t)N_TOK * DIM * 2);
    u16*   wT    = (u16*)alloc(4ull * DIM * DIM * 2);        // wqT,wkT,wvT,wpT
    u16*   qkvB  = (u16*)alloc(3ull * N_TOK * DIM * 2);
    u16*   yB    = (u16*)alloc((size_t)N_TOK * DIM * 2);
    float* x1    = (float*)alloc((size_t)N_TOK * DIM * 4);
    u16*   h2B   = (u16*)alloc((size_t)N_TOK * DIM * 2);
    u16*   winT  = (u16*)alloc((size_t)NE * DIM * FF * 2);
    u16*   woutT = (u16*)alloc((size_t)NE * DIM * FF * 2);
    u16*   mid   = (u16*)alloc((size_t)N_TOK * 2 * FF * 2);
    float* C2    = (float*)alloc((size_t)N_TOK * 2 * DIM * 4);
    float* qkvb  = (float*)alloc(3ull * DIM * 4);
    int*   cnt   = (int*)alloc(NE * 4);
    int*   offp  = (int*)alloc(NE * 4);
    int*   list  = (int*)alloc((size_t)NE * N_TOK * 4);
    int*   tokE  = (int*)alloc((size_t)N_TOK * 2 * 4);
    int*   tokP  = (int*)alloc((size_t)N_TOK * 2 * 4);
    float* tokW  = (float*)alloc((size_t)N_TOK * 2 * 4);

    // weight transposes -> bf16 B^T layout
    transposeK<<<dim3(32, 32, 1), 256, 0, stream>>>(wq, wT + 0ull * DIM * DIM, DIM, DIM, 0, 0);
    transposeK<<<dim3(32, 32, 1), 256, 0, stream>>>(wk, wT + 1ull * DIM * DIM, DIM, DIM, 0, 0);
    transposeK<<<dim3(32, 32, 1), 256, 0, stream>>>(wv, wT + 2ull * DIM * DIM, DIM, DIM, 0, 0);
    transposeK<<<dim3(32, 32, 1), 256, 0, stream>>>(wp, wT + 3ull * DIM * DIM, DIM, DIM, 0, 0);
    transposeK<<<dim3(FF / 32, DIM / 32, NE), 256, 0, stream>>>(w_in, winT, DIM, FF, (long)DIM * FF, (long)DIM * FF);
    transposeK<<<dim3(DIM / 32, FF / 32, NE), 256, 0, stream>>>(w_out, woutT, FF, DIM, (long)DIM * FF, (long)DIM * FF);
    biaspack<<<dim3(3), 256, 0, stream>>>(bq, bk, bv, qkvb);

    // LN1 -> h (bf16)
    ln_kernel<<<dim3(N_TOK), 256, 0, stream>>>(x, ln1g, ln1b, hB);
    // QKV projections -> bf16 (z picks q/k/v)
    gemm_k<3, false, false><<<dim3(DIM / BN, N_TOK / BM, 3), 256, 0, stream>>>(
        hB, 0, wT, (long)DIM * DIM, qkvb, DIM, nullptr, qkvB, (long)N_TOK * DIM,
        nullptr, nullptr, 0, nullptr, nullptr, N_TOK, DIM, DIM);
    // MFMA flash attention -> y (bf16)
    fattn_kernel<<<dim3(SEQ / 128, 2 * NHEAD), 256, 0, stream>>>(qkvB, yB);
    // out projection + residual -> x1 (fp32)
    gemm_k<1, false, false><<<dim3(DIM / BN, N_TOK / BM, 1), 256, 0, stream>>>(
        yB, 0, wT + 3ull * DIM * DIM, 0, bp, 0, x1, nullptr, 0,
        x, nullptr, 0, nullptr, nullptr, N_TOK, DIM, DIM);
    // gating + routing
    hipMemsetAsync(cnt, 0, NE * sizeof(int), stream);
    gate_kernel<<<dim3(N_TOK), 256, 0, stream>>>(
        x1, ln2g, ln2b, wg, bg, wn, bn, noise, h2B,
        out + 2097152, out + 2097152 + 16384,
        cnt, list, tokE, tokP, tokW);
    offs_kernel<<<dim3(1), 64, 0, stream>>>(cnt, offp);
    // expert FFN, sparse grouped: GEMM1 (GELU->bf16 mid), GEMM2 (fp32 C2)
    gemm_k<2, true, true><<<dim3(FF / BN, N_TOK / BM, NE), 256, 0, stream>>>(
        h2B, 0, winT, (long)DIM * FF, b_in, FF, nullptr, mid, 0,
        nullptr, list, N_TOK, cnt, offp, N_TOK, FF, DIM);
    gemm_k<0, false, true><<<dim3(DIM / BN, N_TOK / BM, NE), 256, 0, stream>>>(
        mid, 0, woutT, (long)DIM * FF, b_out, DIM, C2, nullptr, 0,
        nullptr, nullptr, 0, cnt, offp, N_TOK, DIM, FF);
    // combine + residual (original x)
    combine_kernel<<<dim3(N_TOK), 256, 0, stream>>>(x, C2, offp, tokE, tokP, tokW, out);
}

// Round 3
// 744.498 us; speedup vs baseline: 3.0604x; 1.1208x over previous
//
#include <hip/hip_runtime.h>
#include <cmath>

typedef __attribute__((ext_vector_type(4))) float f4;
typedef __attribute__((ext_vector_type(8))) short s8;
typedef unsigned short u16;

#define N_TOK 2048
#define DIM   1024
#define NHEAD 16
#define DH    64
#define NE    8
#define FF    4096
#define SEQ   1024

__device__ __forceinline__ u16 f2bf(float f) {
    union { float fp; unsigned int u; } un; un.fp = f;
    unsigned int r = un.u + 0x7FFFu + ((un.u >> 16) & 1u);
    return (u16)(r >> 16);
}

// ---------------- transpose fp32 [R,C] -> bf16 [C,R] (B^T for GEMM) ----------------
__global__ __launch_bounds__(256) void transposeK(const float* __restrict__ in,
                                                  u16* __restrict__ outp,
                                                  int R, int C, long sInZ, long sOutZ) {
    in += (long)blockIdx.z * sInZ;
    outp += (long)blockIdx.z * sOutZ;
    __shared__ float tile[32][33];
    int c0 = blockIdx.x * 32, r0 = blockIdx.y * 32;
    int c = threadIdx.x & 31, rq = threadIdx.x >> 5;   // rq 0..7
#pragma unroll
    for (int p = 0; p < 4; p++)
        tile[rq + p * 8][c] = in[(long)(r0 + rq + p * 8) * C + c0 + c];
    __syncthreads();
#pragma unroll
    for (int p = 0; p < 4; p++) {
        int cc = rq + p * 8;
        outp[(long)(c0 + cc) * R + r0 + c] = f2bf(tile[c][cc]);
    }
}

__global__ void biaspack(const float* bq, const float* bk, const float* bv, float* dst) {
    int z = blockIdx.x;
    const float* s = (z == 0) ? bq : ((z == 1) ? bk : bv);
    for (int i = threadIdx.x; i < DIM; i += 256) dst[z * DIM + i] = s[i];
}

// ---------------- LayerNorm -> bf16 rows ----------------
__global__ __launch_bounds__(256) void ln_kernel(const float* __restrict__ x,
                                                 const float* __restrict__ g,
                                                 const float* __restrict__ b,
                                                 u16* __restrict__ o) {
    int n = blockIdx.x, tid = threadIdx.x;
    f4 v = ((const f4*)(x + (long)n * DIM))[tid];
    float s = v.x + v.y + v.z + v.w;
    float ss = v.x * v.x + v.y * v.y + v.z * v.z + v.w * v.w;
    __shared__ float red[16];
#pragma unroll
    for (int off = 32; off; off >>= 1) { s += __shfl_down(s, off); ss += __shfl_down(ss, off); }
    int w = tid >> 6;
    if ((tid & 63) == 0) { red[w] = s; red[8 + w] = ss; }
    __syncthreads();
    s = red[0] + red[1] + red[2] + red[3];
    ss = red[8] + red[9] + red[10] + red[11];
    float mu = s * (1.0f / DIM);
    float var = ss * (1.0f / DIM) - mu * mu;
    float rstd = rsqrtf(var + 1e-5f);
    f4 gv = ((const f4*)g)[tid], bv = ((const f4*)b)[tid];
    ushort4 pk;
    pk.x = f2bf((v.x - mu) * rstd * gv.x + bv.x);
    pk.y = f2bf((v.y - mu) * rstd * gv.y + bv.y);
    pk.z = f2bf((v.z - mu) * rstd * gv.z + bv.z);
    pk.w = f2bf((v.w - mu) * rstd * gv.w + bv.w);
    ((ushort4*)(o + (long)n * DIM))[tid] = pk;
}

// ---------------- pipelined 128xBN x32 bf16 MFMA GEMM ----------------
// EPI: 0 = f32 store (split-K capable), 2 = GELU -> bf16, 3 = bf16 store (+z)
#define BM 128
#define BK 32
#define LDK 40

template <int EPI, bool GATHER, bool USEOFF, int BNT, int SPLITK>
__global__ __launch_bounds__(256) void gemm_k(
    const u16* __restrict__ A, long strideAz,
    const u16* __restrict__ BT, long strideBz,
    const float* __restrict__ bias, long strideBiasz,
    float* __restrict__ Cf, u16* __restrict__ Cb, long strideCz, long splitStride,
    const float* __restrict__ res,
    const int* __restrict__ rowlist, int rlStride,
    const int* __restrict__ cnt_p, const int* __restrict__ off_p,
    int M, int N, int K) {
    constexpr int NTv = BNT / 32;   // n-tiles per wave
    int z = blockIdx.z;
    int ze = z / SPLITK, zs = z % SPLITK;
    int Mv = cnt_p ? cnt_p[ze] : M;
    int m0 = blockIdx.y * BM;
    if (m0 >= Mv) return;
    int n0 = blockIdx.x * BNT;
    int off = (USEOFF && off_p) ? off_p[ze] : 0;
    A += ze * strideAz;
    BT += ze * strideBz;
    bias += ze * strideBiasz;
    int Ksp = K / SPLITK;
    int ks = zs * Ksp;

    __shared__ u16 As[2][BM * LDK];
    __shared__ u16 Bs[2][BNT * LDK];

    int tid = threadIdx.x;
    int r0 = tid >> 2, seg = tid & 3;   // r0 0..63, seg 0..3

    auto srcrow = [&](int r) -> long {
        int i = m0 + r;
        if (GATHER) {
            int ii = (i < Mv) ? rowlist[ze * rlStride + i] : 0;
            return (long)ii;
        } else {
            int ii = (i < Mv) ? i : (Mv - 1);
            return (long)ii + (USEOFF ? (long)off : 0L);
        }
    };

    const u16* aBase0 = A + srcrow(r0) * K + ks + seg * 8;
    const u16* aBase1 = A + srcrow(r0 + 64) * K + ks + seg * 8;
    const u16* bBase0 = BT + (long)(n0 + r0) * K + ks + seg * 8;
    const u16* bBase1 = (BNT == 128) ? (BT + (long)(n0 + r0 + 64) * K + ks + seg * 8) : nullptr;

    uint4 va0, va1, vb0, vb1;
    auto loadg = [&](int it) {
        long d = (long)it * BK;
        va0 = *(const uint4*)(aBase0 + d);
        va1 = *(const uint4*)(aBase1 + d);
        vb0 = *(const uint4*)(bBase0 + d);
        if (BNT == 128) vb1 = *(const uint4*)(bBase1 + d);
    };
    auto storlds = [&](int buf) {
        *(uint4*)(As[buf] + r0 * LDK + seg * 8) = va0;
        *(uint4*)(As[buf] + (r0 + 64) * LDK + seg * 8) = va1;
        *(uint4*)(Bs[buf] + r0 * LDK + seg * 8) = vb0;
        if (BNT == 128) *(uint4*)(Bs[buf] + (r0 + 64) * LDK + seg * 8) = vb1;
    };

    int nIter = Ksp / BK;
    loadg(0);
    storlds(0);
    if (nIter > 1) loadg(1);

    f4 acc[4][NTv] = {};
    int lane = tid & 63;
    int w = tid >> 6, wm = w & 1, wn = w >> 1;
    int fr = lane & 15, quad = lane >> 4, kq = quad * 8;

    for (int i = 0; i < nIter; i++) {
        __syncthreads();
        int cur = i & 1;
        s8 af[4], bfv[NTv];
#pragma unroll
        for (int t = 0; t < 4; t++)
            af[t] = *(const s8*)(As[cur] + (wm * 64 + t * 16 + fr) * LDK + kq);
#pragma unroll
        for (int t = 0; t < NTv; t++)
            bfv[t] = *(const s8*)(Bs[cur] + (wn * (BNT / 2) + t * 16 + fr) * LDK + kq);
        if (i + 1 < nIter) storlds(1 - cur);
        if (i + 2 < nIter) loadg(i + 2);
#pragma unroll
        for (int mt = 0; mt < 4; mt++)
#pragma unroll
            for (int nt = 0; nt < NTv; nt++)
                acc[mt][nt] = __builtin_amdgcn_mfma_f32_16x16x32_bf16(af[mt], bfv[nt], acc[mt][nt], 0, 0, 0);
    }

#pragma unroll
    for (int nt = 0; nt < NTv; nt++) {
        int col = n0 + wn * (BNT / 2) + nt * 16 + fr;
        float bv = (SPLITK == 1 || zs == 0) ? bias[col] : 0.0f;
#pragma unroll
        for (int mt = 0; mt < 4; mt++) {
            int rbase = m0 + wm * 64 + mt * 16 + quad * 4;
#pragma unroll
            for (int i = 0; i < 4; i++) {
                int rl = rbase + i;
                if (rl < Mv) {
                    float vvv = acc[mt][nt][i] + bv;
                    long crow = (long)rl + (USEOFF ? off : 0);
                    if (EPI == 0) {
                        Cf[(long)zs * splitStride + ze * strideCz + crow * N + col] = vvv;
                    } else if (EPI == 2) {
                        float gl = 0.5f * vvv * (1.0f + erff(vvv * 0.70710678118654752f));
                        Cb[crow * (long)N + col] = f2bf(gl);
                    } else {
                        Cb[ze * strideCz + crow * (long)N + col] = f2bf(vvv);
                    }
                }
            }
        }
    }
}

// ---------------- split-K reduce: o = P[0..] + P[sp..] (+ res) ----------------
__global__ __launch_bounds__(256) void reduceK(const float* __restrict__ P, long sp,
                                               const float* __restrict__ res,
                                               float* __restrict__ o, int total4) {
    int i = blockIdx.x * 256 + threadIdx.x;
    if (i >= total4) return;
    f4 v = ((const f4*)P)[i] + ((const f4*)(P + sp))[i];
    if (res) v += ((const f4*)res)[i];
    ((f4*)o)[i] = v;
}

// ---------------- MFMA flash attention ----------------
#define ALDK 72

__global__ __launch_bounds__(256) void fattn_kernel(const u16* __restrict__ qkv,
                                                    u16* __restrict__ y) {
    __shared__ u16 Qs[128 * ALDK];
    __shared__ u16 Ks[64 * ALDK];
    __shared__ u16 Vs[64 * ALDK];
    __shared__ u16 Ps[4][32 * ALDK];
    int qt = blockIdx.x;
    int bh = blockIdx.y, b = bh >> 4, h = bh & 15;
    int tid = threadIdx.x, w = tid >> 6, lane = tid & 63;
    int fr = lane & 15, quad = lane >> 4;

    const u16* Qg = qkv + ((long)(b * SEQ + qt * 128) * DIM + h * DH);
    const u16* Kg = qkv + (long)N_TOK * DIM + ((long)b * SEQ * DIM + h * DH);
    const u16* Vg = Kg + (long)N_TOK * DIM;

#pragma unroll
    for (int p = 0; p < 4; p++) {
        int item = tid + p * 256;
        int r = item >> 3, seg = item & 7;
        *(uint4*)(Qs + r * ALDK + seg * 8) = *(const uint4*)(Qg + (long)r * DIM + seg * 8);
    }
    __syncthreads();

    s8 qf[2][2];
    int qrow = w * 32;
#pragma unroll
    for (int mt = 0; mt < 2; mt++)
#pragma unroll
        for (int kk = 0; kk < 2; kk++)
            qf[mt][kk] = *(const s8*)(Qs + (qrow + mt * 16 + fr) * ALDK + kk * 32 + quad * 8);

    f4 o_acc[2][4] = {};
    float m_run[2][4], l_run[2][4];
#pragma unroll
    for (int mt = 0; mt < 2; mt++)
#pragma unroll
        for (int i = 0; i < 4; i++) { m_run[mt][i] = -INFINITY; l_run[mt][i] = 0.f; }

    int qb_wave = qt * 128 + w * 32;
    int nkt = 2 * qt + 2;
    for (int kt = 0; kt < nkt; kt++) {
        __syncthreads();
#pragma unroll
        for (int p = 0; p < 2; p++) {
            int item = tid + p * 256;
            int r = item >> 3, seg = item & 7;
            *(uint4*)(Ks + r * ALDK + seg * 8) =
                *(const uint4*)(Kg + (long)(kt * 64 + r) * DIM + seg * 8);
            uint4 vv = *(const uint4*)(Vg + (long)(kt * 64 + r) * DIM + seg * 8);
            const u16* vp = (const u16*)&vv;
#pragma unroll
            for (int j = 0; j < 8; j++)
                Vs[(seg * 8 + j) * ALDK + r] = vp[j];
        }
        __syncthreads();

        bool act = (kt * 64 <= qb_wave + 31);
        if (act) {
            f4 s_acc[2][4] = {};
#pragma unroll
            for (int kk = 0; kk < 2; kk++) {
                s8 bf[4];
#pragma unroll
                for (int nt = 0; nt < 4; nt++)
                    bf[nt] = *(const s8*)(Ks + (nt * 16 + fr) * ALDK + kk * 32 + quad * 8);
#pragma unroll
                for (int mt = 0; mt < 2; mt++)
#pragma unroll
                    for (int nt = 0; nt < 4; nt++)
                        s_acc[mt][nt] = __builtin_amdgcn_mfma_f32_16x16x32_bf16(
                            qf[mt][kk], bf[nt], s_acc[mt][nt], 0, 0, 0);
            }
#pragma unroll
            for (int mt = 0; mt < 2; mt++)
#pragma unroll
                for (int i = 0; i < 4; i++) {
                    int t_ = qb_wave + mt * 16 + quad * 4 + i;
#pragma unroll
                    for (int nt = 0; nt < 4; nt++) {
                        int s_ = kt * 64 + nt * 16 + fr;
                        float sv = s_acc[mt][nt][i] * 0.125f;
                        s_acc[mt][nt][i] = (s_ <= t_) ? sv : -1e30f;
                    }
                }
#pragma unroll
            for (int mt = 0; mt < 2; mt++)
#pragma unroll
                for (int i = 0; i < 4; i++) {
                    float rm = s_acc[mt][0][i];
#pragma unroll
                    for (int nt = 1; nt < 4; nt++) rm = fmaxf(rm, s_acc[mt][nt][i]);
                    rm = fmaxf(rm, __shfl_xor(rm, 1));
                    rm = fmaxf(rm, __shfl_xor(rm, 2));
                    rm = fmaxf(rm, __shfl_xor(rm, 4));
                    rm = fmaxf(rm, __shfl_xor(rm, 8));
                    float mn = fmaxf(m_run[mt][i], rm);
                    float alpha = __expf(m_run[mt][i] - mn);
                    m_run[mt][i] = mn;
                    float rs = 0.f;
#pragma unroll
                    for (int nt = 0; nt < 4; nt++) {
                        float p = __expf(s_acc[mt][nt][i] - mn);
                        s_acc[mt][nt][i] = p;
                        rs += p;
                    }
                    rs += __shfl_xor(rs, 1);
                    rs += __shfl_xor(rs, 2);
                    rs += __shfl_xor(rs, 4);
                    rs += __shfl_xor(rs, 8);
                    l_run[mt][i] = alpha * l_run[mt][i] + rs;
#pragma unroll
                    for (int dt = 0; dt < 4; dt++) o_acc[mt][dt][i] *= alpha;
                }
            u16* Pw = Ps[w];
#pragma unroll
            for (int mt = 0; mt < 2; mt++)
#pragma unroll
                for (int nt = 0; nt < 4; nt++)
#pragma unroll
                    for (int i = 0; i < 4; i++)
                        Pw[(mt * 16 + quad * 4 + i) * ALDK + nt * 16 + fr] =
                            f2bf(s_acc[mt][nt][i]);
        }
        __syncthreads();
        if (act) {
            u16* Pw = Ps[w];
#pragma unroll
            for (int kk = 0; kk < 2; kk++) {
                s8 pf[2], vf[4];
#pragma unroll
                for (int mt = 0; mt < 2; mt++)
                    pf[mt] = *(const s8*)(Pw + (mt * 16 + fr) * ALDK + kk * 32 + quad * 8);
#pragma unroll
                for (int dt = 0; dt < 4; dt++)
                    vf[dt] = *(const s8*)(Vs + (dt * 16 + fr) * ALDK + kk * 32 + quad * 8);
#pragma unroll
                for (int mt = 0; mt < 2; mt++)
#pragma unroll
                    for (int dt = 0; dt < 4; dt++)
                        o_acc[mt][dt] = __builtin_amdgcn_mfma_f32_16x16x32_bf16(
                            pf[mt], vf[dt], o_acc[mt][dt], 0, 0, 0);
            }
        }
    }
#pragma unroll
    for (int mt = 0; mt < 2; mt++)
#pragma unroll
        for (int i = 0; i < 4; i++) {
            float linv = 1.0f / l_run[mt][i];
            int t_ = qt * 128 + w * 32 + mt * 16 + quad * 4 + i;
            u16* yrow = y + (long)(b * SEQ + t_) * DIM + h * DH;
#pragma unroll
            for (int dt = 0; dt < 4; dt++)
                yrow[dt * 16 + fr] = f2bf(o_acc[mt][dt][i] * linv);
        }
}

// ---------------- LN2 + gating + routing (fp32 exact logits) ----------------
__global__ __launch_bounds__(256) void gate_kernel(
    const float* __restrict__ x1, const float* __restrict__ g, const float* __restrict__ b,
    const float* __restrict__ wg, const float* __restrict__ bg,
    const float* __restrict__ wn, const float* __restrict__ bn,
    const float* __restrict__ noise, u16* __restrict__ h2,
    float* __restrict__ out_noisy, float* __restrict__ out_gate,
    int* __restrict__ cnt, int* __restrict__ list,
    int* __restrict__ tokE, int* __restrict__ tokP, float* __restrict__ tokW) {
    __shared__ float hrow[DIM];
    __shared__ float red[256 * 16];
    __shared__ float red8[16];
    int n = blockIdx.x, tid = threadIdx.x;
    f4 v = ((const f4*)(x1 + (long)n * DIM))[tid];
    float s = v.x + v.y + v.z + v.w;
    float ss = v.x * v.x + v.y * v.y + v.z * v.z + v.w * v.w;
#pragma unroll
    for (int off = 32; off; off >>= 1) { s += __shfl_down(s, off); ss += __shfl_down(ss, off); }
    int wv_ = tid >> 6;
    if ((tid & 63) == 0) { red8[wv_] = s; red8[8 + wv_] = ss; }
    __syncthreads();
    s = red8[0] + red8[1] + red8[2] + red8[3];
    ss = red8[8] + red8[9] + red8[10] + red8[11];
    float mu = s * (1.0f / DIM);
    float var = ss * (1.0f / DIM) - mu * mu;
    float rstd = rsqrtf(var + 1e-5f);
    f4 gv = ((const f4*)g)[tid], bv = ((const f4*)b)[tid];
    float h0 = (v.x - mu) * rstd * gv.x + bv.x;
    float h1 = (v.y - mu) * rstd * gv.y + bv.y;
    float h2v = (v.z - mu) * rstd * gv.z + bv.z;
    float h3 = (v.w - mu) * rstd * gv.w + bv.w;
    hrow[tid * 4 + 0] = h0; hrow[tid * 4 + 1] = h1;
    hrow[tid * 4 + 2] = h2v; hrow[tid * 4 + 3] = h3;
    ushort4 pk;
    pk.x = f2bf(h0); pk.y = f2bf(h1); pk.z = f2bf(h2v); pk.w = f2bf(h3);
    ((ushort4*)(h2 + (long)n * DIM))[tid] = pk;
    __syncthreads();
    float ag[8] = {0, 0, 0, 0, 0, 0, 0, 0}, an[8] = {0, 0, 0, 0, 0, 0, 0, 0};
    for (int d = tid; d < DIM; d += 256) {
        float hv = hrow[d];
        const f4* wgp = (const f4*)(wg + (long)d * NE);
        f4 w0 = wgp[0], w1 = wgp[1];
        ag[0] += hv * w0.x; ag[1] += hv * w0.y; ag[2] += hv * w0.z; ag[3] += hv * w0.w;
        ag[4] += hv * w1.x; ag[5] += hv * w1.y; ag[6] += hv * w1.z; ag[7] += hv * w1.w;
        const f4* wnp = (const f4*)(wn + (long)d * NE);
        f4 n0v = wnp[0], n1v = wnp[1];
        an[0] += hv * n0v.x; an[1] += hv * n0v.y; an[2] += hv * n0v.z; an[3] += hv * n0v.w;
        an[4] += hv * n1v.x; an[5] += hv * n1v.y; an[6] += hv * n1v.z; an[7] += hv * n1v.w;
    }
#pragma unroll
    for (int j = 0; j < 8; j++) { red[tid * 16 + j] = ag[j]; red[tid * 16 + 8 + j] = an[j]; }
    __syncthreads();
    for (int st = 128; st > 0; st >>= 1) {
        if (tid < st) {
#pragma unroll
            for (int j = 0; j < 16; j++) red[tid * 16 + j] += red[(tid + st) * 16 + j];
        }
        __syncthreads();
    }
    if (tid == 0) {
        float gl[8], nl[8], ny[8];
#pragma unroll
        for (int e = 0; e < 8; e++) { gl[e] = red[e] + bg[e]; nl[e] = red[8 + e] + bn[e]; }
#pragma unroll
        for (int e = 0; e < 8; e++) {
            float xx = nl[e];
            float sp = (xx > 20.f) ? xx : log1pf(expf(xx));
            ny[e] = gl[e] + noise[(long)n * 8 + e] * sp;
        }
#pragma unroll
        for (int e = 0; e < 8; e++) {
            out_noisy[(long)n * 8 + e] = ny[e];
            out_gate[(long)n * 8 + e] = gl[e];
        }
        float mx = ny[0];
#pragma unroll
        for (int e = 1; e < 8; e++) mx = fmaxf(mx, ny[e]);
        float p[8], sum = 0.f;
#pragma unroll
        for (int e = 0; e < 8; e++) { p[e] = expf(ny[e] - mx); sum += p[e]; }
        int e1 = 0;
#pragma unroll
        for (int e = 1; e < 8; e++) if (p[e] > p[e1]) e1 = e;
        int e2 = (e1 == 0) ? 1 : 0;
#pragma unroll
        for (int e = 0; e < 8; e++) if (e != e1 && p[e] > p[e2]) e2 = e;
        float wsum = p[e1] + p[e2];
        float w1 = p[e1] / wsum, w2 = p[e2] / wsum;
        int q1 = atomicAdd(&cnt[e1], 1);
        list[e1 * N_TOK + q1] = n; tokE[2 * n] = e1; tokP[2 * n] = q1; tokW[2 * n] = w1;
        int q2 = atomicAdd(&cnt[e2], 1);
        list[e2 * N_TOK + q2] = n; tokE[2 * n + 1] = e2; tokP[2 * n + 1] = q2; tokW[2 * n + 1] = w2;
    }
}

__global__ void offs_kernel(const int* __restrict__ cnt, int* __restrict__ off) {
    if (threadIdx.x == 0) {
        int a = 0;
#pragma unroll
        for (int e = 0; e < NE; e++) { off[e] = a; a += cnt[e]; }
    }
}

__global__ __launch_bounds__(256) void combine_kernel(
    const float* __restrict__ x, const float* __restrict__ C2, const int* __restrict__ offp,
    const int* __restrict__ tokE, const int* __restrict__ tokP, const float* __restrict__ tokW,
    float* __restrict__ out) {
    int n = blockIdx.x, tid = threadIdx.x;
    int e0 = tokE[2 * n], e1 = tokE[2 * n + 1];
    long s0 = (long)offp[e0] + tokP[2 * n];
    long s1 = (long)offp[e1] + tokP[2 * n + 1];
    float w0 = tokW[2 * n], w1 = tokW[2 * n + 1];
    f4 xv = ((const f4*)(x + (long)n * DIM))[tid];
    f4 a = ((const f4*)(C2 + s0 * DIM))[tid];
    f4 b = ((const f4*)(C2 + s1 * DIM))[tid];
    f4 o = xv + w0 * a + w1 * b;
    ((f4*)(out + (long)n * DIM))[tid] = o;
}

// ---------------- host ----------------
extern "C" void kernel_launch(void* const* d_in, const int* in_sizes, int n_in,
                              void* d_out, int out_size, void* d_ws, size_t ws_size,
                              hipStream_t stream) {
    (void)in_sizes; (void)n_in; (void)out_size; (void)ws_size;
    const float* x     = (const float*)d_in[0];
    const float* noise = (const float*)d_in[1];
    const float* ln1g  = (const float*)d_in[2];
    const float* ln1b  = (const float*)d_in[3];
    const float* ln2g  = (const float*)d_in[4];
    const float* ln2b  = (const float*)d_in[5];
    const float* wq = (const float*)d_in[6];  const float* bq = (const float*)d_in[7];
    const float* wk = (const float*)d_in[8];  const float* bk = (const float*)d_in[9];
    const float* wv = (const float*)d_in[10]; const float* bv = (const float*)d_in[11];
    const float* wp = (const float*)d_in[12]; const float* bp = (const float*)d_in[13];
    const float* wg = (const float*)d_in[14]; const float* bg = (const float*)d_in[15];
    const float* wn = (const float*)d_in[16]; const float* bn = (const float*)d_in[17];
    const float* w_in  = (const float*)d_in[18]; const float* b_in  = (const float*)d_in[19];
    const float* w_out = (const float*)d_in[20]; const float* b_out = (const float*)d_in[21];
    float* out = (float*)d_out;

    char* ws = (char*)d_ws;
    size_t o = 0;
    auto alloc = [&](size_t sz) -> char* { char* p = ws + o; o += (sz + 255) & ~(size_t)255; return p; };
    u16*   hB    = (u16*)alloc((size_t)N_TOK * DIM * 2);
    u16*   wT    = (u16*)alloc(4ull * DIM * DIM * 2);        // wqT,wkT,wvT,wpT
    u16*   qkvB  = (u16*)alloc(3ull * N_TOK * DIM * 2);      // 12 MB (aliased as MoE split1 later)
    u16*   yB    = (u16*)alloc((size_t)N_TOK * DIM * 2);     //  4 MB (contiguous with qkvB)
    float* x1    = (float*)alloc((size_t)N_TOK * DIM * 4);
    u16*   h2B   = (u16*)alloc((size_t)N_TOK * DIM * 2);
    u16*   winT  = (u16*)alloc((size_t)NE * DIM * FF * 2);
    u16*   woutT = (u16*)alloc((size_t)NE * DIM * FF * 2);
    u16*   mid   = (u16*)alloc((size_t)N_TOK * 2 * FF * 2);
    float* C2    = (float*)alloc((size_t)N_TOK * 2 * DIM * 4);  // 16 MB (also proj split buf)
    float* qkvb  = (float*)alloc(3ull * DIM * 4);
    int*   cnt   = (int*)alloc(NE * 4);
    int*   offp  = (int*)alloc(NE * 4);
    int*   list  = (int*)alloc((size_t)NE * N_TOK * 4);
    int*   tokE  = (int*)alloc((size_t)N_TOK * 2 * 4);
    int*   tokP  = (int*)alloc((size_t)N_TOK * 2 * 4);
    float* tokW  = (float*)alloc((size_t)N_TOK * 2 * 4);

    // weight transposes -> bf16 B^T layout
    transposeK<<<dim3(32, 32, 1), 256, 0, stream>>>(wq, wT + 0ull * DIM * DIM, DIM, DIM, 0, 0);
    transposeK<<<dim3(32, 32, 1), 256, 0, stream>>>(wk, wT + 1ull * DIM * DIM, DIM, DIM, 0, 0);
    transposeK<<<dim3(32, 32, 1), 256, 0, stream>>>(wv, wT + 2ull * DIM * DIM, DIM, DIM, 0, 0);
    transposeK<<<dim3(32, 32, 1), 256, 0, stream>>>(wp, wT + 3ull * DIM * DIM, DIM, DIM, 0, 0);
    transposeK<<<dim3(FF / 32, DIM / 32, NE), 256, 0, stream>>>(w_in, winT, DIM, FF, (long)DIM * FF, (long)DIM * FF);
    transposeK<<<dim3(DIM / 32, FF / 32, NE), 256, 0, stream>>>(w_out, woutT, FF, DIM, (long)DIM * FF, (long)DIM * FF);
    biaspack<<<dim3(3), 256, 0, stream>>>(bq, bk, bv, qkvb);

    // LN1 -> h (bf16)
    ln_kernel<<<dim3(N_TOK), 256, 0, stream>>>(x, ln1g, ln1b, hB);
    // QKV projections -> bf16, BN=64 for block count (768 blocks)
    gemm_k<3, false, false, 64, 1><<<dim3(DIM / 64, N_TOK / BM, 3), 256, 0, stream>>>(
        hB, 0, wT, (long)DIM * DIM, qkvb, DIM, nullptr, qkvB, (long)N_TOK * DIM, 0,
        nullptr, nullptr, 0, nullptr, nullptr, N_TOK, DIM, DIM);
    // MFMA flash attention -> y (bf16)
    fattn_kernel<<<dim3(SEQ / 128, 2 * NHEAD), 256, 0, stream>>>(qkvB, yB);
    // out projection: split-K x2 into C2 region, then reduce + residual -> x1
    gemm_k<0, false, false, 64, 2><<<dim3(DIM / 64, N_TOK / BM, 2), 256, 0, stream>>>(
        yB, 0, wT + 3ull * DIM * DIM, 0, bp, 0, C2, nullptr, 0, (long)N_TOK * DIM,
        nullptr, nullptr, 0, nullptr, nullptr, N_TOK, DIM, DIM);
    reduceK<<<dim3(N_TOK * DIM / 4 / 256), 256, 0, stream>>>(
        C2, (long)N_TOK * DIM, x, x1, N_TOK * DIM / 4);
    // gating + routing
    hipMemsetAsync(cnt, 0, NE * sizeof(int), stream);
    gate_kernel<<<dim3(N_TOK), 256, 0, stream>>>(
        x1, ln2g, ln2b, wg, bg, wn, bn, noise, h2B,
        out + 2097152, out + 2097152 + 16384,
        cnt, list, tokE, tokP, tokW);
    offs_kernel<<<dim3(1), 64, 0, stream>>>(cnt, offp);
    // expert FFN GEMM1 (gathered rows, GELU -> bf16 mid), BN=128
    gemm_k<2, true, true, 128, 1><<<dim3(FF / 128, N_TOK / BM, NE), 256, 0, stream>>>(
        h2B, 0, winT, (long)DIM * FF, b_in, FF, nullptr, mid, 0, 0,
        nullptr, list, N_TOK, cnt, offp, N_TOK, FF, DIM);
    // expert FFN GEMM2: split-K x2, split0 -> C2, split1 -> (qkvB|yB) alias region
    {
        long s1off = (long)((float*)qkvB - C2);   // float-element offset between buffers
        gemm_k<0, false, true, 64, 2><<<dim3(DIM / 64, N_TOK / BM, NE * 2), 256, 0, stream>>>(
            mid, 0, woutT, (long)DIM * FF, b_out, DIM, C2, nullptr, 0, s1off,
            nullptr, nullptr, 0, cnt, offp, N_TOK, DIM, FF);
        reduceK<<<dim3(2 * N_TOK * DIM / 4 / 256), 256, 0, stream>>>(
            C2, s1off, nullptr, C2, 2 * N_TOK * DIM / 4);
    }
    // combine + residual (original x)
    combine_kernel<<<dim3(N_TOK), 256, 0, stream>>>(x, C2, offp, tokE, tokP, tokW, out);
}